// Round 5
// baseline (5023.900 us; speedup 1.0000x reference)
//
#include <hip/hip_runtime.h>
#include <math.h>

// ---------------------------------------------------------------------------
// RITS forward, round 5: per-row-independent recurrence, 128 blocks x 1024
// threads. Gate GEMM ([c_c,m]@W_ih^T + hd@W_hh^T) in int8 sdot4 with
// per-column weight scales (prep) + dynamic c_c scale per step (shfl max).
// Small GEMVs stay f16 fdot2. Weights stream from L2 each step (~736 KiB).
// B=256, L=256, D=128, H=256.
// ---------------------------------------------------------------------------

namespace {
constexpr int Bn = 256, Ln = 256, Dn = 128, Hn = 256;
constexpr long LD = (long)Ln * Dn;  // 32768

// ws byte offsets
constexpr int OFF_LOSS  = 0;
constexpr int OFF_DEN   = 256;      // 256 f32
constexpr int OFF_BIASG = 2048;     // 1024 f32 [jj][q]
constexpr int OFF_SW    = 8192;     // 4096 f32 scales sw[s*1024+col]
constexpr int OFF_WQ8   = 24576;    // 512 KiB i8 gate weights
                                    //   uint4 idx = ((s*8+k16)*4+q)*256 + jj
constexpr int OFF_HISTP = 548864;   // 16384 dw [kp<128][d<128]
constexpr int OFF_TDHP  = 614400;   // 16384 dw [kp<64][h<256]
constexpr int OFF_WFP   = 679936;   // 8192 dw  [kp<64][d<128] (diag=0)
constexpr int OFF_WCP   = 712704;   // 16384 dw [kp<128][d<128]

constexpr int DSM_FLOATS = 8224 + 4096;           // scratch + sw_s
constexpr int DSM_BYTES  = DSM_FLOATS * 4;        // 49280
}  // namespace

typedef _Float16 h2f __attribute__((ext_vector_type(2)));
typedef unsigned int uint32;

__device__ __forceinline__ float fdot2(uint32 a, uint32 b, float c) {
  return __builtin_amdgcn_fdot2(__builtin_bit_cast(h2f, a),
                                __builtin_bit_cast(h2f, b), c, false);
}
__device__ __forceinline__ int sdot4(uint32 a, uint32 b, int c) {
  return __builtin_amdgcn_sdot4((int)a, (int)b, c, false);
}
__device__ __forceinline__ uint32 packf16(float a, float b) {
  h2f p; p[0] = (_Float16)a; p[1] = (_Float16)b;
  return __builtin_bit_cast(uint32, p);
}
__device__ __forceinline__ unsigned short f16u(float a) {
  _Float16 h = (_Float16)a; return __builtin_bit_cast(unsigned short, h);
}

// ======================= K1: repack + biases + denom ========================
__global__ void rits_prep(const float* __restrict__ td_h_W,
                          const float* __restrict__ hist_W,
                          const float* __restrict__ feat_W,
                          const float* __restrict__ wc_W,
                          const float* __restrict__ W_ih,
                          const float* __restrict__ W_hh,
                          const float* __restrict__ b_ih,
                          const float* __restrict__ b_hh,
                          const float* __restrict__ evalm,
                          char* __restrict__ wsb) {
  const int blk = blockIdx.x, tid = threadIdx.x;
  if (blk < 16) {  // i8 gate-weight pack: task = (s<4, col<1024)
    int task = blk * 256 + tid;
    int s = task >> 10, col = task & 1023;
    int q = col >> 8, jj = col & 255;
    const float* src = ((s < 2) ? W_ih : W_hh) + (size_t)col * 256 + (s & 1) * 128;
    float mx = 0.f;
    for (int k = 0; k < 128; k += 4) {
      float4 v = *(const float4*)(src + k);
      mx = fmaxf(mx, fmaxf(fmaxf(fabsf(v.x), fabsf(v.y)),
                           fmaxf(fabsf(v.z), fabsf(v.w))));
    }
    float inv = mx > 0.f ? 127.f / mx : 0.f;
    ((float*)(wsb + OFF_SW))[s * 1024 + col] = mx / 127.f;
    for (int k16 = 0; k16 < 8; ++k16) {
      uint32 dw[4];
      for (int d4 = 0; d4 < 4; ++d4) {
        uint32 v = 0;
        for (int j = 0; j < 4; ++j) {
          int qv = __float2int_rn(src[k16 * 16 + d4 * 4 + j] * inv);
          qv = qv < -127 ? -127 : (qv > 127 ? 127 : qv);
          v |= ((uint32)(qv & 0xff)) << (8 * j);
        }
        dw[d4] = v;
      }
      uint4 u = {dw[0], dw[1], dw[2], dw[3]};
      ((uint4*)(wsb + OFF_WQ8))[((s * 8 + k16) * 4 + q) * 256 + jj] = u;
    }
  } else if (blk < 80) {  // histP f16 pairs [kp<128][d<128]
    int i2 = (blk - 16) * 256 + tid, kp = i2 >> 7, d = i2 & 127;
    ((uint32*)(wsb + OFF_HISTP))[i2] =
        packf16(hist_W[d * 256 + 2 * kp], hist_W[d * 256 + 2 * kp + 1]);
  } else if (blk < 144) {  // tdhP [kp<64][h<256]
    int i2 = (blk - 80) * 256 + tid, kp = i2 >> 8, h = i2 & 255;
    ((uint32*)(wsb + OFF_TDHP))[i2] =
        packf16(td_h_W[h * 128 + 2 * kp], td_h_W[h * 128 + 2 * kp + 1]);
  } else if (blk < 176) {  // wfP [kp<64][d<128], diag=0
    int i2 = (blk - 144) * 256 + tid, kp = i2 >> 7, d = i2 & 127;
    float a = (2 * kp == d) ? 0.f : feat_W[d * 128 + 2 * kp];
    float b = (2 * kp + 1 == d) ? 0.f : feat_W[d * 128 + 2 * kp + 1];
    ((uint32*)(wsb + OFF_WFP))[i2] = packf16(a, b);
  } else if (blk < 240) {  // wcP [kp<128][d<128]
    int i2 = (blk - 176) * 256 + tid, kp = i2 >> 7, d = i2 & 127;
    ((uint32*)(wsb + OFF_WCP))[i2] =
        packf16(wc_W[d * 256 + 2 * kp], wc_W[d * 256 + 2 * kp + 1]);
  } else if (blk < 244) {  // biasg
    int i = (blk - 240) * 256 + tid;
    int jj = i >> 2, q = i & 3;
    ((float*)(wsb + OFF_BIASG))[jj * 4 + q] =
        b_ih[q * 256 + jj] + b_hh[q * 256 + jj];
    if (blk == 240 && tid == 0) *((float*)(wsb + OFF_LOSS)) = 0.f;
  } else {  // denom per t
    int t = blk - 244;
    __shared__ float red[256];
    int d = tid & 127, g = tid >> 7;
    float s = 0.f;
    for (int b = g; b < 256; b += 2) s += evalm[(size_t)b * LD + t * 128 + d];
    red[tid] = s;
    __syncthreads();
    for (int o = 128; o > 0; o >>= 1) {
      if (tid < o) red[tid] += red[tid + o];
      __syncthreads();
    }
    if (tid == 0) ((float*)(wsb + OFF_DEN))[t] = red[0] + 1e-5f;
  }
}

// ========================== K2: recurrent blocks ============================
extern __shared__ __align__(16) char dsm[];

__global__ __launch_bounds__(1024, 4) void rits_rec(
    const float* __restrict__ values, const float* __restrict__ masks,
    const float* __restrict__ deltas, const float* __restrict__ evalm,
    const float* __restrict__ td_h_b, const float* __restrict__ td_x_w,
    const float* __restrict__ td_x_b, const float* __restrict__ hist_b,
    const float* __restrict__ feat_b, const float* __restrict__ wc_b,
    char* __restrict__ wsb, float* __restrict__ outp) {
  float* scratch = (float*)dsm;          // 8224 f32 (phase partials; i32 in H)
  int* scratchI = (int*)dsm;
  float* sw_s = scratch + 8224;          // 4096 f32 gate-weight scales

  __shared__ float den_s[256], bg_s[1024], tdhb_s[256];
  __shared__ float txw_s[128], txb_s[128], hb_s[128], fb_s[128], wcb_s[128];
  __shared__ float hf[2][256], cst[2][256];
  __shared__ float xs[2][128], ms[2][128], es[2][128];
  __shared__ float xh_s[2][128], al_s[2][128];
  __shared__ __align__(8) unsigned short hdU16[128 * 4];  // h f16 pairs (for x_h)
  __shared__ __align__(8) unsigned short xcU16[64 * 4];   // x_c f16 pairs (for z)
  __shared__ uint32 drP[64 * 2];    // deltas f16 pairs [kp][r]
  __shared__ uint32 gxmP[128 * 2];  // [gamma_x|m] f16 pairs [kp][r]
  __shared__ __align__(16) uint4 cc8u4[2][8];   // c_c i8 [r][128]
  __shared__ __align__(16) uint4 m8u4[2][8];    // m i8 (exact)
  __shared__ __align__(16) uint4 hd8u4[2][16];  // hd i8, fixed x127
  __shared__ float s_cc_s;

  const int tid = threadIdx.x;
  const size_t b0 = (size_t)blockIdx.x * 2;
  const uint32* hdU32 = (const uint32*)hdU16;
  const uint32* xcU32 = (const uint32*)xcU16;
  const uint4* histP4 = (const uint4*)(wsb + OFF_HISTP);
  const uint4* tdhP4 = (const uint4*)(wsb + OFF_TDHP);
  const uint4* wfP4 = (const uint4*)(wsb + OFF_WFP);
  const uint4* wcP4 = (const uint4*)(wsb + OFF_WCP);
  const uint4* wq8 = (const uint4*)(wsb + OFF_WQ8);

  // -------- preload / init --------
  if (tid < 512) { ((float*)hf)[tid] = 0.f; ((float*)cst)[tid] = 0.f; }
  bg_s[tid] = ((const float*)(wsb + OFF_BIASG))[tid];
#pragma unroll
  for (int i = 0; i < 4; ++i)
    sw_s[tid + i * 1024] = ((const float*)(wsb + OFF_SW))[tid + i * 1024];
  if (tid < 256) {
    den_s[tid] = ((const float*)(wsb + OFF_DEN))[tid];
    tdhb_s[tid] = td_h_b[tid];
  } else if (tid < 384) txw_s[tid - 256] = td_x_w[tid - 256];
  else if (tid < 512) txb_s[tid - 384] = td_x_b[tid - 384];
  else if (tid < 640) hb_s[tid - 512] = hist_b[tid - 512];
  else if (tid < 768) fb_s[tid - 640] = feat_b[tid - 640];
  else if (tid < 896) wcb_s[tid - 768] = wc_b[tid - 768];
  __syncthreads();

  float lacc = 0.f;
  for (int t = 0; t < Ln; ++t) {
    const size_t base = b0 * LD + (size_t)t * 128;
    float cc_reg = 0.f;
    // ---- A: stage inputs; gamma_x & m f16 pairs; m i8 ----
    if (tid < 256) {
      int d = tid & 127, r = tid >> 7;
      size_t gi = base + (size_t)r * LD + d;
      float vv = values[gi], mm = masks[gi];
      xs[r][d] = vv;
      ms[r][d] = mm;
      es[r][d] = evalm[gi];
      ((signed char*)m8u4)[r * 128 + d] = (signed char)mm;  // exact 0/1
    } else if (tid < 512) {
      int i = tid - 256, kp = i & 127, r = i >> 7;
      size_t gb = base + (size_t)r * LD;
      if (kp < 64) {
        float d0v = deltas[gb + 2 * kp], d1v = deltas[gb + 2 * kp + 1];
        drP[kp * 2 + r] = packf16(d0v, d1v);
        float g0 = __expf(-fmaxf(fmaf(d0v, txw_s[2 * kp], txb_s[2 * kp]), 0.f));
        float g1 = __expf(-fmaxf(fmaf(d1v, txw_s[2 * kp + 1], txb_s[2 * kp + 1]), 0.f));
        gxmP[kp * 2 + r] = packf16(g0, g1);
      } else {
        int k2 = kp - 64;
        gxmP[kp * 2 + r] = packf16(masks[gb + 2 * k2], masks[gb + 2 * k2 + 1]);
      }
    }
    __syncthreads();

    // ---- B: gamma_h partials (256 thr) | alpha partials (512 thr) ----
    if (tid < 256) {
      int g = tid & 63, r = (tid >> 6) & 1, kq = tid >> 7;
      float4 a = {0.f, 0.f, 0.f, 0.f};
#pragma unroll 4
      for (int i = 0; i < 32; ++i) {
        int kp = kq * 32 + i;
        uint4 w = tdhP4[kp * 64 + g];
        uint32 dr = drP[kp * 2 + r];
        a.x = fdot2(dr, w.x, a.x); a.y = fdot2(dr, w.y, a.y);
        a.z = fdot2(dr, w.z, a.z); a.w = fdot2(dr, w.w, a.w);
      }
      ((float4*)(scratch + (kq * 2 + r) * 260))[g] = a;
    } else if (tid < 768) {
      int i0 = tid - 256, g = i0 & 31, r = (i0 >> 5) & 1, kq = i0 >> 6;
      float4 a = {0.f, 0.f, 0.f, 0.f};
#pragma unroll 4
      for (int i = 0; i < 16; ++i) {
        int kp = kq * 16 + i;
        uint4 w = wcP4[kp * 32 + g];
        uint32 gm = gxmP[kp * 2 + r];
        a.x = fdot2(gm, w.x, a.x); a.y = fdot2(gm, w.y, a.y);
        a.z = fdot2(gm, w.z, a.z); a.w = fdot2(gm, w.w, a.w);
      }
      ((float4*)(scratch + 1040 + (kq * 2 + r) * 132))[g] = a;
    }
    __syncthreads();

    // ---- C: reduce gamma_h -> hd (f16 pairs + i8) ; reduce alpha ----
    if (tid < 512) {
      int h = tid & 255, r = tid >> 8;
      float s = scratch[r * 260 + h] + scratch[(2 + r) * 260 + h] + tdhb_s[h];
      float hd = hf[r][h] * __expf(-fmaxf(s, 0.f));
      hdU16[(h >> 1) * 4 + 2 * r + (h & 1)] = f16u(hd);
      ((signed char*)hd8u4)[r * 256 + h] = (signed char)__float2int_rn(hd * 127.f);
    } else if (tid < 768) {
      int i0 = tid - 512, d = i0 & 127, r = i0 >> 7;
      float s = wcb_s[d];
#pragma unroll
      for (int kq = 0; kq < 8; ++kq) s += scratch[1040 + (kq * 2 + r) * 132 + d];
      al_s[r][d] = s;
    }
    __syncthreads();

    // ---- D: x_h partials (f16) ----
    if (tid < 512) {
      int g = tid & 31, r = (tid >> 5) & 1, kq = tid >> 6;
      float4 a = {0.f, 0.f, 0.f, 0.f};
#pragma unroll 4
      for (int i = 0; i < 16; ++i) {
        int kp = kq * 16 + i;
        uint4 w = histP4[kp * 32 + g];
        uint32 hd = hdU32[kp * 2 + r];
        a.x = fdot2(hd, w.x, a.x); a.y = fdot2(hd, w.y, a.y);
        a.z = fdot2(hd, w.z, a.z); a.w = fdot2(hd, w.w, a.w);
      }
      ((float4*)(scratch + (kq * 2 + r) * 132))[g] = a;
    }
    __syncthreads();

    // ---- E: x_h, x_c ; pack x_c f16 pairs ----
    if (tid < 256) {
      int d = tid & 127, r = tid >> 7;
      float xh = hb_s[d];
#pragma unroll
      for (int kq = 0; kq < 8; ++kq) xh += scratch[(kq * 2 + r) * 132 + d];
      xh_s[r][d] = xh;
      float mm = ms[r][d];
      float xc = mm * xs[r][d] + (1.f - mm) * xh;
      xcU16[(d >> 1) * 4 + 2 * r + (d & 1)] = f16u(xc);
    }
    __syncthreads();

    // ---- F: z partials (f16) ----
    if (tid < 512) {
      int g = tid & 31, r = (tid >> 5) & 1, kq = tid >> 6;
      float4 a = {0.f, 0.f, 0.f, 0.f};
#pragma unroll 4
      for (int i = 0; i < 8; ++i) {
        int kp = kq * 8 + i;
        uint4 w = wfP4[kp * 32 + g];
        uint32 xc = xcU32[kp * 2 + r];
        a.x = fdot2(xc, w.x, a.x); a.y = fdot2(xc, w.y, a.y);
        a.z = fdot2(xc, w.z, a.z); a.w = fdot2(xc, w.w, a.w);
      }
      ((float4*)(scratch + (kq * 2 + r) * 132))[g] = a;
    }
    __syncthreads();

    // ---- G: c_h, c_c, out, loss; wave-max |c_c| ----
    if (tid < 256) {
      int d = tid & 127, r = tid >> 7;
      float z = fb_s[d];
#pragma unroll
      for (int kq = 0; kq < 8; ++kq) z += scratch[(kq * 2 + r) * 132 + d];
      float a = al_s[r][d], xh = xh_s[r][d];
      float ch = a * z + (1.f - a) * xh;
      float mm = ms[r][d], xv = xs[r][d];
      float cc = mm * xv + (1.f - mm) * ch;
      outp[base + (size_t)r * LD + d] = cc;
      lacc += (1.f - mm) * fabsf(ch - xv) * es[r][d] / den_s[t];
      cc_reg = cc;
      float am = fabsf(cc);
#pragma unroll
      for (int off = 32; off > 0; off >>= 1) am = fmaxf(am, __shfl_xor(am, off));
      if ((tid & 63) == 0) scratch[8208 + (tid >> 6)] = am;
    }
    __syncthreads();

    // ---- G2: quantize c_c with dynamic scale ----
    if (tid < 256) {
      int d = tid & 127, r = tid >> 7;
      float mx = fmaxf(fmaxf(scratch[8208], scratch[8209]),
                       fmaxf(scratch[8210], scratch[8211]));
      float inv = mx > 0.f ? 127.f / mx : 0.f;
      if (tid == 0) s_cc_s = mx / 127.f;
      float v = fminf(fmaxf(cc_reg * inv, -127.f), 127.f);
      ((signed char*)cc8u4)[r * 128 + d] = (signed char)__float2int_rn(v);
    }
    __syncthreads();

    // ---- H: i8 gate partials: tid = jj(256) x s(4) ----
    {
      int jj = tid & 255, s = tid >> 8;
      const uint4* wp = wq8 + (size_t)s * 8192 + jj;  // [k16*1024 + q*256]
      const uint4* a0p;
      const uint4* a1p;
      if (s == 0) { a0p = cc8u4[0]; a1p = cc8u4[1]; }
      else if (s == 1) { a0p = m8u4[0]; a1p = m8u4[1]; }
      else { a0p = hd8u4[0] + (s - 2) * 8; a1p = hd8u4[1] + (s - 2) * 8; }
      int acc[8] = {0, 0, 0, 0, 0, 0, 0, 0};
#pragma unroll
      for (int k16 = 0; k16 < 8; ++k16) {
        uint4 a0 = a0p[k16], a1 = a1p[k16];
#pragma unroll
        for (int q = 0; q < 4; ++q) {
          uint4 w = wp[k16 * 1024 + q * 256];
          acc[q * 2 + 0] = sdot4(w.w, a0.w, sdot4(w.z, a0.z,
                           sdot4(w.y, a0.y, sdot4(w.x, a0.x, acc[q * 2 + 0]))));
          acc[q * 2 + 1] = sdot4(w.w, a1.w, sdot4(w.z, a1.z,
                           sdot4(w.y, a1.y, sdot4(w.x, a1.x, acc[q * 2 + 1]))));
        }
      }
#pragma unroll
      for (int i = 0; i < 8; ++i) scratchI[(s * 8 + i) * 257 + jj] = acc[i];
    }
    __syncthreads();

    // ---- I: combine scaled gate partials + LSTM ----
    if (tid < 256) {
      int jj = tid;
      float scc = s_cc_s;
      const float inv127 = 1.f / 127.f;
#pragma unroll
      for (int r = 0; r < 2; ++r) {
        float gq[4];
#pragma unroll
        for (int q = 0; q < 4; ++q) {
          int col = q * 256 + jj;
          float a0 = (float)scratchI[(0 * 8 + q * 2 + r) * 257 + jj];
          float a1 = (float)scratchI[(1 * 8 + q * 2 + r) * 257 + jj];
          float a2 = (float)scratchI[(2 * 8 + q * 2 + r) * 257 + jj];
          float a3 = (float)scratchI[(3 * 8 + q * 2 + r) * 257 + jj];
          gq[q] = bg_s[jj * 4 + q] + scc * sw_s[col] * a0 + sw_s[1024 + col] * a1 +
                  inv127 * (sw_s[2048 + col] * a2 + sw_s[3072 + col] * a3);
        }
        float ig = 1.f / (1.f + __expf(-gq[0]));
        float fg = 1.f / (1.f + __expf(-gq[1]));
        float gg = tanhf(gq[2]);
        float og = 1.f / (1.f + __expf(-gq[3]));
        float c = fg * cst[r][jj] + ig * gg;
        cst[r][jj] = c;
        hf[r][jj] = og * tanhf(c);
      }
    }
    __syncthreads();
  }

  // -------- loss reduce --------
  scratch[tid] = lacc;
  __syncthreads();
  for (int o = 512; o > 0; o >>= 1) {
    if (tid < o) scratch[tid] += scratch[tid + o];
    __syncthreads();
  }
  if (tid == 0) atomicAdd((float*)(wsb + OFF_LOSS), scratch[0]);
}

// ========================== K3: loss scalar =================================
__global__ void rits_fin(const char* __restrict__ wsb, float* __restrict__ outp) {
  if (threadIdx.x == 0 && blockIdx.x == 0)
    outp[(size_t)Bn * LD] = *((const float*)(wsb + OFF_LOSS));
}

// ============================== launcher ====================================
extern "C" void kernel_launch(void* const* d_in, const int* in_sizes, int n_in,
                              void* d_out, int out_size, void* d_ws,
                              size_t ws_size, hipStream_t stream) {
  const float* values = (const float*)d_in[0];
  const float* masks  = (const float*)d_in[1];
  const float* deltas = (const float*)d_in[2];
  const float* evalm  = (const float*)d_in[3];
  const float* td_h_W = (const float*)d_in[4];
  const float* td_h_b = (const float*)d_in[5];
  const float* td_x_w = (const float*)d_in[6];
  const float* td_x_b = (const float*)d_in[7];
  const float* hist_W = (const float*)d_in[8];
  const float* hist_b = (const float*)d_in[9];
  const float* feat_W = (const float*)d_in[10];
  const float* feat_b = (const float*)d_in[11];
  const float* wc_W   = (const float*)d_in[12];
  const float* wc_b   = (const float*)d_in[13];
  const float* W_ih   = (const float*)d_in[14];
  const float* W_hh   = (const float*)d_in[15];
  const float* b_ih   = (const float*)d_in[16];
  const float* b_hh   = (const float*)d_in[17];
  char* wsb = (char*)d_ws;
  float* outp = (float*)d_out;

  hipFuncSetAttribute((const void*)rits_rec,
                      hipFuncAttributeMaxDynamicSharedMemorySize, DSM_BYTES);
  hipLaunchKernelGGL(rits_prep, dim3(500), dim3(256), 0, stream, td_h_W,
                     hist_W, feat_W, wc_W, W_ih, W_hh, b_ih, b_hh, evalm, wsb);
  hipLaunchKernelGGL(rits_rec, dim3(128), dim3(1024), DSM_BYTES, stream,
                     values, masks, deltas, evalm, td_h_b, td_x_w, td_x_b,
                     hist_b, feat_b, wc_b, wsb, outp);
  hipLaunchKernelGGL(rits_fin, dim3(1), dim3(64), 0, stream, wsb, outp);
}